// Round 14
// baseline (222.065 us; speedup 1.0000x reference)
//
#include <hip/hip_runtime.h>
#include <hip/hip_bf16.h>
#include <cstddef>

#define DIMK 512
#define HEADS 8
#define DHEAD 64
#define NSEQ 2048
#define NB 8
#define M_TOT (NB * NSEQ)   // 16384

typedef __attribute__((ext_vector_type(8))) short bf16x8;
typedef __attribute__((ext_vector_type(4))) float f32x4;
typedef __attribute__((ext_vector_type(2))) unsigned int u32x2;

__device__ __forceinline__ unsigned short f2bf(float f) {
    union { float f; unsigned int u; } v; v.f = f;
    unsigned int r = v.u + 0x7fffu + ((v.u >> 16) & 1u);   // round-nearest-even
    return (unsigned short)(r >> 16);
}

// pack two fp32 -> two trunc-bf16 in one dword: hi<<16 | lo  (1 VALU op)
__device__ __forceinline__ unsigned int pk_bf_trunc(float hi, float lo) {
    union { float f; unsigned int u; } a, b; a.f = hi; b.f = lo;
    return __builtin_amdgcn_perm(a.u, b.u, 0x07060302u);
}

// native 2^x (Q is pre-scaled by log2(e)*exp(log_scale) so this is the whole exp)
__device__ __forceinline__ float fexp2(float x) {
#if __has_builtin(__builtin_amdgcn_exp2f)
    return __builtin_amdgcn_exp2f(x);
#else
    return __expf(x * 0.69314718056f);
#endif
}

// async 16B/lane global->LDS. LDS dest is wave-uniform base + lane*16.
__device__ __forceinline__ void glds16(const unsigned short* g, unsigned short* l) {
    __builtin_amdgcn_global_load_lds(
        (const __attribute__((address_space(1))) void*)g,
        (__attribute__((address_space(3))) void*)l, 16, 0, 0);
}

// Quad-redistribution for the PV B-fragment (replaces the Pq LDS round-trip).
// Verified on-HW in R11 (pass, absmax bit-identical to the Pq version).
__device__ __forceinline__ void redist(unsigned u, unsigned v, bool qodd,
                                       unsigned &dlo, unsigned &dhi) {
    u32x2 s = __builtin_amdgcn_permlane32_swap(u, v, false, false);
    const unsigned za = __builtin_amdgcn_ds_swizzle(s.x, 0x401F);
    const unsigned zb = __builtin_amdgcn_ds_swizzle(s.y, 0x401F);
    dlo = qodd ? zb : s.x;
    dhi = qodd ? s.y : za;
}

// ---------------------------------------------------------------------------
// Merged pre-pass (R10-verified): one launch replaces f32_to_bf16 +
// transpose_both.  Blocks [0,4096): x fp32 -> bf16 row-major.
// Blocks [4096,5120): weights KxN fp32 -> [N][512] bf16 transpose
// (Q-columns get exp(log_scale)*log2(e) folded).
// ---------------------------------------------------------------------------
__global__ __launch_bounds__(256) void prepass(
    const float* __restrict__ x, const float* __restrict__ w_qkv,
    const float* __restrict__ w_out, unsigned short* __restrict__ xb,
    unsigned short* __restrict__ WqT, unsigned short* __restrict__ WoT,
    const float* __restrict__ log_scale)
{
    __shared__ float t[32][33];
    if (blockIdx.x < 4096) {
        const size_t i = ((size_t)blockIdx.x * 256 + threadIdx.x) * 8;
        const float4 a = *(const float4*)(x + i);
        const float4 b = *(const float4*)(x + i + 4);
        bf16x8 o;
        o[0] = (short)f2bf(a.x); o[1] = (short)f2bf(a.y);
        o[2] = (short)f2bf(a.z); o[3] = (short)f2bf(a.w);
        o[4] = (short)f2bf(b.x); o[5] = (short)f2bf(b.y);
        o[6] = (short)f2bf(b.z); o[7] = (short)f2bf(b.w);
        *(bf16x8*)(xb + i) = o;
    } else {
        const int bb = blockIdx.x - 4096;   // 0..1023
        const int bx = bb & 63;             // 0..63
        const int by = bb >> 6;             // 0..15
        const int tx = threadIdx.x & 31, ty = threadIdx.x >> 5;
        const int k0 = by * 32;
        const float* W; unsigned short* WT; int N, n0;
        float sc = 1.0f;
        if (bx < 48) {
            W = w_qkv; WT = WqT; N = 1536; n0 = bx * 32;
            if (n0 < 512) sc = __expf(log_scale[0]) * 1.4426950408889634f;
        } else {
            W = w_out; WT = WoT; N = 512; n0 = (bx - 48) * 32;
        }
        #pragma unroll
        for (int s = 0; s < 32; s += 8)
            t[ty + s][tx] = W[(size_t)(k0 + ty + s) * N + n0 + tx];
        __syncthreads();
        #pragma unroll
        for (int s = 0; s < 32; s += 8)
            WT[(size_t)(n0 + ty + s) * DIMK + k0 + tx] = f2bf(t[tx][ty + s] * sc);
    }
}

// ---------------------------------------------------------------------------
// MFMA GEMM 1 (R14): BK=64 mainloop (R9-harness-verified body — 8 barrier
// drains instead of 16; As/Bs 32KB inside the 34.8KB pool, 4 blocks/CU
// UNCHANGED, removing R9's gemm_out occupancy confound) + R13-verified
// transposed epilogues (Q/K [row][col], V [col][row] -> 16B/lane stores).
// K-accum order preserved (kk=0,1 == two BK=32 steps) -> bit-identical.
// ---------------------------------------------------------------------------
__global__ __launch_bounds__(256) void gemm_qkv_mfma(
    const unsigned short* __restrict__ Xb, const unsigned short* __restrict__ WT,
    unsigned short* __restrict__ Qb, unsigned short* __restrict__ Kb,
    unsigned short* __restrict__ VTb)
{
    // pool: mainloop uses [0..16383] as As/Bs ([128][64] each); epilogues
    // reuse all 17408 shorts as a [128][136] transpose buffer.
    __shared__ __align__(16) unsigned short pool[128 * 136];   // 34816 B
    unsigned short* As = pool;           // [128][64]
    unsigned short* Bs = pool + 8192;    // [128][64]
    const int tid = threadIdx.x, wave = tid >> 6, lane = tid & 63;
    const int l16 = lane & 15, quad = lane >> 4;
    const int m0 = blockIdx.x * 128;
    const int cb = blockIdx.y;
    const int col0 = cb * 128;
    const int wrow = wave >> 1, wcol = wave & 1;

    // staging: each wave owns 32 rows (4 glds16 of 8 rows each) of A and B
    const int srow   = lane >> 3;          // 0..7
    const int schunk = (lane & 7) * 8;     // 16B chunk within 64-elem row
    const unsigned short* gA = Xb + (size_t)(m0 + wave * 32 + srow) * DIMK + schunk;
    const unsigned short* gB = WT + (size_t)(col0 + wave * 32 + srow) * DIMK + schunk;
    unsigned short* lA = As + (wave * 32) * 64;
    unsigned short* lB = Bs + (wave * 32) * 64;

    f32x4 acc[4][4];
    #pragma unroll
    for (int i = 0; i < 4; ++i)
        #pragma unroll
        for (int j = 0; j < 4; ++j) acc[i][j] = (f32x4){0.f, 0.f, 0.f, 0.f};

    for (int k0 = 0; k0 < DIMK; k0 += 64) {
        __syncthreads();
        glds16(gA + k0,                      lA);
        glds16(gA + (size_t) 8 * DIMK + k0,  lA + 512);
        glds16(gA + (size_t)16 * DIMK + k0,  lA + 1024);
        glds16(gA + (size_t)24 * DIMK + k0,  lA + 1536);
        glds16(gB + k0,                      lB);
        glds16(gB + (size_t) 8 * DIMK + k0,  lB + 512);
        glds16(gB + (size_t)16 * DIMK + k0,  lB + 1024);
        glds16(gB + (size_t)24 * DIMK + k0,  lB + 1536);
        __syncthreads();
        #pragma unroll
        for (int kk = 0; kk < 2; ++kk) {
            bf16x8 af[4], bfr[4];
            #pragma unroll
            for (int i = 0; i < 4; ++i)
                af[i] = *(const bf16x8*)(As + (wrow * 64 + i * 16 + l16) * 64 + kk * 32 + quad * 8);
            #pragma unroll
            for (int j = 0; j < 4; ++j)
                bfr[j] = *(const bf16x8*)(Bs + (wcol * 64 + j * 16 + l16) * 64 + kk * 32 + quad * 8);
            #pragma unroll
            for (int i = 0; i < 4; ++i)
                #pragma unroll
                for (int j = 0; j < 4; ++j)
                    acc[i][j] = __builtin_amdgcn_mfma_f32_16x16x32_bf16(af[i], bfr[j], acc[i][j], 0, 0, 0);
        }
    }

    const int which = cb >> 2;   // 0=Q 1=K 2=V, uniform per block
    const int bb   = m0 >> 11;
    const int n0g  = m0 & 2047;
    const int w0   = col0 & 511;
    if (which == 2) {
        // ---- V: LDS-transposed epilogue ([col][row] staging) ----
        __syncthreads();   // everyone done with As/Bs; reuse pool
        #pragma unroll
        for (int i = 0; i < 4; ++i) {
            #pragma unroll
            for (int j = 0; j < 4; ++j) {
                const int c  = wcol * 64 + j * 16 + l16;
                const int n0 = wrow * 64 + i * 16 + quad * 4;
                uint2 w;
                w.x = (unsigned int)f2bf(acc[i][j][0]) | ((unsigned int)f2bf(acc[i][j][1]) << 16);
                w.y = (unsigned int)f2bf(acc[i][j][2]) | ((unsigned int)f2bf(acc[i][j][3]) << 16);
                *(uint2*)(&pool[c * 136 + n0]) = w;
            }
        }
        __syncthreads();
        const int cbase = tid >> 4;     // 0..15
        const int ln16  = tid & 15;
        #pragma unroll
        for (int pass = 0; pass < 8; ++pass) {
            const int cc = pass * 16 + cbase;           // 0..127
            const int w  = w0 + cc;
            const int h  = w >> 6, d = w & 63;
            const size_t bh = (size_t)(bb * HEADS + h);
            const bf16x8 val = *(const bf16x8*)(&pool[cc * 136 + ln16 * 8]);
            *(bf16x8*)(VTb + (bh * DHEAD + d) * NSEQ + n0g + ln16 * 8) = val;
        }
    } else {
        // ---- Q/K: LDS-transposed epilogue ([row][col] staging, R13) ----
        unsigned short* dstb = (which == 0) ? Qb : Kb;
        __syncthreads();   // everyone done with As/Bs; reuse pool
        #pragma unroll
        for (int i = 0; i < 4; ++i) {
            #pragma unroll
            for (int j = 0; j < 4; ++j) {
                const int c  = wcol * 64 + j * 16 + l16;
                const int r0 = wrow * 64 + i * 16 + quad * 4;
                #pragma unroll
                for (int r = 0; r < 4; ++r)
                    pool[(r0 + r) * 136 + c] = f2bf(acc[i][j][r]);
            }
        }
        __syncthreads();
        const int cbase = tid >> 4;     // 0..15 (row group)
        const int ln16  = tid & 15;     // 8-col chunk
        const int w     = w0 + ln16 * 8;
        const int h     = w >> 6, d = w & 63;
        const size_t bh = (size_t)(bb * HEADS + h);
        #pragma unroll
        for (int pass = 0; pass < 8; ++pass) {
            const int row = pass * 16 + cbase;          // 0..127
            const int n   = n0g + row;
            const bf16x8 val = *(const bf16x8*)(&pool[row * 136 + ln16 * 8]);
            *(bf16x8*)(dstb + (bh * NSEQ + n) * DHEAD + d) = val;
        }
    }
}

// ---------------------------------------------------------------------------
// MFMA GEMM 2 (R8-verified, BK=32 — kept small: 16KB LDS = 8 blocks/CU; the
// R9 regression was this kernel's 32KB/5-block variant).
// out = O @ w_out + b_out (fp32 output).
// ---------------------------------------------------------------------------
__global__ __launch_bounds__(256) void gemm_out_mfma(
    const unsigned short* __restrict__ Ab, const unsigned short* __restrict__ BT,
    const float* __restrict__ bias, float* __restrict__ C)
{
    __shared__ unsigned short As[128 * 32];
    __shared__ unsigned short Bs[128 * 32];
    const int tid = threadIdx.x, wave = tid >> 6, lane = tid & 63;
    const int l16 = lane & 15, quad = lane >> 4;
    const int m0 = blockIdx.x * 128, col0 = blockIdx.y * 128;
    const int wrow = wave >> 1, wcol = wave & 1;

    unsigned short* lA0 = As + (wave * 16) * 32;
    unsigned short* lA1 = As + (64 + wave * 16) * 32;
    unsigned short* lB0 = Bs + (wave * 16) * 32;
    unsigned short* lB1 = Bs + (64 + wave * 16) * 32;
    const unsigned short* gA = Ab + (size_t)(m0 + wave * 16 + (lane >> 2)) * DIMK + (lane & 3) * 8;
    const unsigned short* gB = BT + (size_t)(col0 + wave * 16 + (lane >> 2)) * DIMK + (lane & 3) * 8;

    f32x4 acc[4][4];
    #pragma unroll
    for (int i = 0; i < 4; ++i)
        #pragma unroll
        for (int j = 0; j < 4; ++j) acc[i][j] = (f32x4){0.f, 0.f, 0.f, 0.f};

    for (int k0 = 0; k0 < DIMK; k0 += 32) {
        __syncthreads();
        glds16(gA + k0, lA0);
        glds16(gA + (size_t)64 * DIMK + k0, lA1);
        glds16(gB + k0, lB0);
        glds16(gB + (size_t)64 * DIMK + k0, lB1);
        __syncthreads();
        bf16x8 af[4], bfr[4];
        #pragma unroll
        for (int i = 0; i < 4; ++i)
            af[i] = *(const bf16x8*)(As + (wrow * 64 + i * 16 + l16) * 32 + quad * 8);
        #pragma unroll
        for (int j = 0; j < 4; ++j)
            bfr[j] = *(const bf16x8*)(Bs + (wcol * 64 + j * 16 + l16) * 32 + quad * 8);
        #pragma unroll
        for (int i = 0; i < 4; ++i)
            #pragma unroll
            for (int j = 0; j < 4; ++j)
                acc[i][j] = __builtin_amdgcn_mfma_f32_16x16x32_bf16(af[i], bfr[j], acc[i][j], 0, 0, 0);
    }

    #pragma unroll
    for (int i = 0; i < 4; ++i) {
        #pragma unroll
        for (int r = 0; r < 4; ++r) {
            const int gr = m0 + wrow * 64 + i * 16 + quad * 4 + r;
            #pragma unroll
            for (int j = 0; j < 4; ++j) {
                const int col = col0 + wcol * 64 + j * 16 + l16;
                C[(size_t)gr * 512 + col] = acc[i][j][r] + bias[col];
            }
        }
    }
}

// ---------------------------------------------------------------------------
// Flash attention v14 (R11/R13-verified, 87.7-90.4us): 8 waves/512 threads,
// Q-tile 256, KVBLK=64, chunk-swizzled glds16 staging, in-register permlane
// transport for P (no Pq LDS), 32KB LDS, VGPR 60.
// Grid: linear%8 == bh%8 pins each head-batch to one XCD (K/V L2-resident).
// ---------------------------------------------------------------------------
__global__ __launch_bounds__(512) void attn_mfma(
    const unsigned short* __restrict__ Qb, const unsigned short* __restrict__ Kb,
    const unsigned short* __restrict__ VTb, unsigned short* __restrict__ O)
{
    __shared__ unsigned short Ks0[2][64 * 32];   // keys x d[0:32)   (chunk-swz)
    __shared__ unsigned short Ks1[2][64 * 32];   // keys x d[32:64)  (chunk-swz)
    __shared__ unsigned short VsA[2][64 * 32];   // d x keys[0:32)   (chunk-swz)
    __shared__ unsigned short VsB[2][64 * 32];   // d x keys[32:64)  (chunk-swz)

    const int tid  = threadIdx.x;
    const int wave = tid >> 6;                 // 0..7
    const int lane = tid & 63;
    const int l16  = lane & 15;
    const int quad = lane >> 4;
    const int bh   = blockIdx.x;               // XCD partition key
    const int q0   = blockIdx.y * 256;
    const int qwA  = q0 + wave * 16;           // group A: rows q0..q0+127
    const int qwB  = q0 + 128 + wave * 16;     // group B: rows q0+128..q0+255

    const unsigned short* Qg = Qb  + (size_t)bh * NSEQ * DHEAD;
    const unsigned short* Kg = Kb  + (size_t)bh * NSEQ * DHEAD;
    const unsigned short* Vg = VTb + (size_t)bh * DHEAD * NSEQ;

    // Q B-fragments for both groups, resident all kernel
    const bf16x8 b_qA0 = *(const bf16x8*)(Qg + (size_t)(qwA + l16) * DHEAD + quad * 8);
    const bf16x8 b_qA1 = *(const bf16x8*)(Qg + (size_t)(qwA + l16) * DHEAD + 32 + quad * 8);
    const bf16x8 b_qB0 = *(const bf16x8*)(Qg + (size_t)(qwB + l16) * DHEAD + quad * 8);
    const bf16x8 b_qB1 = *(const bf16x8*)(Qg + (size_t)(qwB + l16) * DHEAD + 32 + quad * 8);

    // constant all-ones A fragment: row-sum of P via the matrix pipe
    bf16x8 a_ones;
    #pragma unroll
    for (int i = 0; i < 8; ++i) a_ones[i] = (short)0x3F80;   // bf16 1.0

    // staging roles (wave-uniform): dest = wave>>1 (Ks0,Ks1,VsA,VsB),
    // half = wave&1 (32-row half of that dest).  2 glds16 per wave per tile.
    const int dst   = wave >> 1;
    const int halfw = wave & 1;
    const int r16 = lane >> 2;                              // 0..15 (group-local row)
    const int c8s = (((lane & 3) ^ ((lane >> 4) & 3))) * 8; // swizzled 16B chunk
    const unsigned short* gsrc;
    size_t rstep;                         // elems between 16-row groups
    size_t istep;                         // elems per 64-key iteration
    unsigned short* db[2];
    if (dst == 0) {
        gsrc = Kg + (size_t)(halfw * 32 + r16) * DHEAD + c8s;
        rstep = (size_t)16 * DHEAD;  istep = (size_t)64 * DHEAD;
        db[0] = &Ks0[0][halfw * 1024];  db[1] = &Ks0[1][halfw * 1024];
    } else if (dst == 1) {
        gsrc = Kg + (size_t)(halfw * 32 + r16) * DHEAD + 32 + c8s;
        rstep = (size_t)16 * DHEAD;  istep = (size_t)64 * DHEAD;
        db[0] = &Ks1[0][halfw * 1024];  db[1] = &Ks1[1][halfw * 1024];
    } else if (dst == 2) {
        gsrc = Vg + (size_t)(halfw * 32 + r16) * NSEQ + c8s;
        rstep = (size_t)16 * NSEQ;   istep = 64;
        db[0] = &VsA[0][halfw * 1024];  db[1] = &VsA[1][halfw * 1024];
    } else {
        gsrc = Vg + (size_t)(halfw * 32 + r16) * NSEQ + 32 + c8s;
        rstep = (size_t)16 * NSEQ;   istep = 64;
        db[0] = &VsB[0][halfw * 1024];  db[1] = &VsB[1][halfw * 1024];
    }

    // swizzled read slot (group-local row of any t-tile is l16)
    const int ksl = (quad ^ ((l16 >> 2) & 3)) * 8;

    f32x4 oA[4], oB[4], laccA, laccB;
    #pragma unroll
    for (int t = 0; t < 4; ++t) { oA[t] = (f32x4){0.f,0.f,0.f,0.f}; oB[t] = (f32x4){0.f,0.f,0.f,0.f}; }
    laccA = (f32x4){0.f,0.f,0.f,0.f};
    laccB = (f32x4){0.f,0.f,0.f,0.f};

    // prologue: stage tile 0 into buffer 0
    {
        unsigned short* d0 = db[0];
        glds16(gsrc,         d0);
        glds16(gsrc + rstep, d0 + 512);
        gsrc += istep;
    }

    #pragma unroll 2
    for (int it = 0; it < NSEQ / 64; ++it) {
        const int cur = it & 1;
        const int j0  = it * 64;
        __syncthreads();   // buffer `cur` staged; everyone done with `cur^1`

        if (it < NSEQ / 64 - 1) {   // prefetch next tile into the other buffer
            unsigned short* dn = db[cur ^ 1];
            glds16(gsrc,         dn);
            glds16(gsrc + rstep, dn + 512);
            gsrc += istep;
        }

        // ---- S^T = K Q^T (4 m-tiles of 16 keys); p = exp2(s); diag mask ----
        float pA[4][4], pB[4][4];
        #pragma unroll
        for (int t = 0; t < 4; ++t) {
            const bf16x8 a0 = *(const bf16x8*)(&Ks0[cur][(t * 16 + l16) * 32 + ksl]);
            const bf16x8 a1 = *(const bf16x8*)(&Ks1[cur][(t * 16 + l16) * 32 + ksl]);
            f32x4 sA = (f32x4){0.f,0.f,0.f,0.f}, sB = (f32x4){0.f,0.f,0.f,0.f};
            sA = __builtin_amdgcn_mfma_f32_16x16x32_bf16(a0, b_qA0, sA, 0, 0, 0);
            sA = __builtin_amdgcn_mfma_f32_16x16x32_bf16(a1, b_qA1, sA, 0, 0, 0);
            sB = __builtin_amdgcn_mfma_f32_16x16x32_bf16(a0, b_qB0, sB, 0, 0, 0);
            sB = __builtin_amdgcn_mfma_f32_16x16x32_bf16(a1, b_qB1, sB, 0, 0, 0);
            #pragma unroll
            for (int r = 0; r < 4; ++r) { pA[t][r] = fexp2(sA[r]); pB[t][r] = fexp2(sB[r]); }
            if (j0 + 16 * t == qwA) {   // wave-uniform
                #pragma unroll
                for (int r = 0; r < 4; ++r) if (l16 == quad * 4 + r) pA[t][r] = 0.f;
            }
            if (j0 + 16 * t == qwB) {
                #pragma unroll
                for (int r = 0; r < 4; ++r) if (l16 == quad * 4 + r) pB[t][r] = 0.f;
            }
        }

        // ---- pack P dwords; in-register quad redistribution ----
        unsigned wAx[4], wAy[4], wBx[4], wBy[4];
        #pragma unroll
        for (int t = 0; t < 4; ++t) {
            wAx[t] = pk_bf_trunc(pA[t][1], pA[t][0]);
            wAy[t] = pk_bf_trunc(pA[t][3], pA[t][2]);
            wBx[t] = pk_bf_trunc(pB[t][1], pB[t][0]);
            wBy[t] = pk_bf_trunc(pB[t][3], pB[t][2]);
        }
        union U8 { unsigned u[4]; bf16x8 v; } fA0, fA1, fB0, fB1;
        const bool qodd = (quad & 1) != 0;
        redist(wAx[0], wAx[1], qodd, fA0.u[0], fA0.u[2]);
        redist(wAy[0], wAy[1], qodd, fA0.u[1], fA0.u[3]);
        redist(wAx[2], wAx[3], qodd, fA1.u[0], fA1.u[2]);
        redist(wAy[2], wAy[3], qodd, fA1.u[1], fA1.u[3]);
        redist(wBx[0], wBx[1], qodd, fB0.u[0], fB0.u[2]);
        redist(wBy[0], wBy[1], qodd, fB0.u[1], fB0.u[3]);
        redist(wBx[2], wBx[3], qodd, fB1.u[0], fB1.u[2]);
        redist(wBy[2], wBy[3], qodd, fB1.u[1], fB1.u[3]);
        const bf16x8 b_pA0 = fA0.v, b_pA1 = fA1.v;
        const bf16x8 b_pB0 = fB0.v, b_pB1 = fB1.v;

        // ---- row-sums via ones-MFMA; O^T += V^T P^T (two 32-key halves) ----
        laccA = __builtin_amdgcn_mfma_f32_16x16x32_bf16(a_ones, b_pA0, laccA, 0, 0, 0);
        laccA = __builtin_amdgcn_mfma_f32_16x16x32_bf16(a_ones, b_pA1, laccA, 0, 0, 0);
        laccB = __builtin_amdgcn_mfma_f32_16x16x32_bf16(a_ones, b_pB0, laccB, 0, 0, 0);
        laccB = __builtin_amdgcn_mfma_f32_16x16x32_bf16(a_ones, b_pB1, laccB, 0, 0, 0);
        #pragma unroll
        for (int t = 0; t < 4; ++t) {
            const bf16x8 vA = *(const bf16x8*)(&VsA[cur][(t * 16 + l16) * 32 + ksl]);
            const bf16x8 vB = *(const bf16x8*)(&VsB[cur][(t * 16 + l16) * 32 + ksl]);
            oA[t] = __builtin_amdgcn_mfma_f32_16x16x32_bf16(vA, b_pA0, oA[t], 0, 0, 0);
            oA[t] = __builtin_amdgcn_mfma_f32_16x16x32_bf16(vB, b_pA1, oA[t], 0, 0, 0);
            oB[t] = __builtin_amdgcn_mfma_f32_16x16x32_bf16(vA, b_pB0, oB[t], 0, 0, 0);
            oB[t] = __builtin_amdgcn_mfma_f32_16x16x32_bf16(vB, b_pB1, oB[t], 0, 0, 0);
        }
    }

    // ---- epilogue: l is per-lane in every acc reg ----
    const float invA = 1.0f / laccA[0];
    const float invB = 1.0f / laccB[0];
    const int bb = bh >> 3, h = bh & 7;
    {
        const int n = qwA + l16;
        unsigned short* Orow = O + ((size_t)(bb * NSEQ + n)) * 512 + h * 64;
        #pragma unroll
        for (int t = 0; t < 4; ++t) {
            ushort4 o4;
            o4.x = f2bf(oA[t][0] * invA); o4.y = f2bf(oA[t][1] * invA);
            o4.z = f2bf(oA[t][2] * invA); o4.w = f2bf(oA[t][3] * invA);
            *(ushort4*)(Orow + t * 16 + quad * 4) = o4;
        }
    }
    {
        const int n = qwB + l16;
        unsigned short* Orow = O + ((size_t)(bb * NSEQ + n)) * 512 + h * 64;
        #pragma unroll
        for (int t = 0; t < 4; ++t) {
            ushort4 o4;
            o4.x = f2bf(oB[t][0] * invB); o4.y = f2bf(oB[t][1] * invB);
            o4.z = f2bf(oB[t][2] * invB); o4.w = f2bf(oB[t][3] * invB);
            *(ushort4*)(Orow + t * 16 + quad * 4) = o4;
        }
    }
}

extern "C" void kernel_launch(void* const* d_in, const int* in_sizes, int n_in,
                              void* d_out, int out_size, void* d_ws, size_t ws_size,
                              hipStream_t stream) {
    const float* x         = (const float*)d_in[0];
    const float* w_qkv     = (const float*)d_in[1];
    const float* w_out     = (const float*)d_in[2];
    const float* b_out     = (const float*)d_in[3];
    const float* log_scale = (const float*)d_in[4];
    float* out = (float*)d_out;

    char* ws = (char*)d_ws;
    const size_t NQKV = (size_t)NB * HEADS * NSEQ * DHEAD;        // 8,388,608 elems
    unsigned short* xb  = (unsigned short*)(ws);
    unsigned short* Qb  = (unsigned short*)(ws + 2 * NQKV);
    unsigned short* Kb  = (unsigned short*)(ws + 4 * NQKV);
    unsigned short* VTb = (unsigned short*)(ws + 6 * NQKV);
    unsigned short* Ofb = (unsigned short*)(ws + 8 * NQKV);
    unsigned short* WqT = (unsigned short*)(ws + 10 * NQKV);
    unsigned short* WoT = (unsigned short*)(ws + 10 * NQKV + 4 * 1024 * 1024);

    prepass<<<4096 + 1024, 256, 0, stream>>>(x, w_qkv, w_out, xb, WqT, WoT, log_scale);

    gemm_qkv_mfma<<<dim3(M_TOT / 128, 1536 / 128), 256, 0, stream>>>(xb, WqT, Qb, Kb, VTb);

    attn_mfma<<<dim3(NB * HEADS, NSEQ / 256), 512, 0, stream>>>(Qb, Kb, VTb, Ofb);

    gemm_out_mfma<<<dim3(M_TOT / 128, 512 / 128), 256, 0, stream>>>(Ofb, WoT, b_out, out);
}

// Round 15
// 215.301 us; speedup vs baseline: 1.0314x; 1.0314x over previous
//
#include <hip/hip_runtime.h>
#include <hip/hip_bf16.h>
#include <cstddef>

#define DIMK 512
#define HEADS 8
#define DHEAD 64
#define NSEQ 2048
#define NB 8
#define M_TOT (NB * NSEQ)   // 16384

typedef __attribute__((ext_vector_type(8))) short bf16x8;
typedef __attribute__((ext_vector_type(4))) float f32x4;
typedef __attribute__((ext_vector_type(2))) unsigned int u32x2;

__device__ __forceinline__ unsigned short f2bf(float f) {
    union { float f; unsigned int u; } v; v.f = f;
    unsigned int r = v.u + 0x7fffu + ((v.u >> 16) & 1u);   // round-nearest-even
    return (unsigned short)(r >> 16);
}

// pack two fp32 -> two trunc-bf16 in one dword: hi<<16 | lo  (1 VALU op)
__device__ __forceinline__ unsigned int pk_bf_trunc(float hi, float lo) {
    union { float f; unsigned int u; } a, b; a.f = hi; b.f = lo;
    return __builtin_amdgcn_perm(a.u, b.u, 0x07060302u);
}

// native 2^x (Q is pre-scaled by log2(e)*exp(log_scale) so this is the whole exp)
__device__ __forceinline__ float fexp2(float x) {
#if __has_builtin(__builtin_amdgcn_exp2f)
    return __builtin_amdgcn_exp2f(x);
#else
    return __expf(x * 0.69314718056f);
#endif
}

// async 16B/lane global->LDS. LDS dest is wave-uniform base + lane*16.
__device__ __forceinline__ void glds16(const unsigned short* g, unsigned short* l) {
    __builtin_amdgcn_global_load_lds(
        (const __attribute__((address_space(1))) void*)g,
        (__attribute__((address_space(3))) void*)l, 16, 0, 0);
}

// Quad-redistribution for the PV B-fragment (replaces the Pq LDS round-trip).
// R11-HW-verified mapping:
//   dlo: qeven -> s.x,        qodd -> swz16(s.y)
//   dhi: qeven -> swz16(s.x), qodd -> s.y
// R15: ONE ds_swizzle instead of two via partner-select — each lane only
// consumes one cross term, and the xor-16 partner of a qodd lane is qeven,
// so pre-selecting w = qodd ? s.x : s.y (the value the PARTNER needs) makes
// z = swz16(w) deliver s.y[i^16] on qodd lanes and s.x[i^16] on qeven lanes.
// Values bit-identical; -8 DS ops (+8 cndmask) per iteration.
__device__ __forceinline__ void redist(unsigned u, unsigned v, bool qodd,
                                       unsigned &dlo, unsigned &dhi) {
    u32x2 s = __builtin_amdgcn_permlane32_swap(u, v, false, false);
    const unsigned w = qodd ? s.x : s.y;
    const unsigned z = __builtin_amdgcn_ds_swizzle(w, 0x401F);
    dlo = qodd ? z : s.x;
    dhi = qodd ? s.y : z;
}

// ---------------------------------------------------------------------------
// Merged pre-pass (R10-verified): one launch replaces f32_to_bf16 +
// transpose_both.  Blocks [0,4096): x fp32 -> bf16 row-major.
// Blocks [4096,5120): weights KxN fp32 -> [N][512] bf16 transpose
// (Q-columns get exp(log_scale)*log2(e) folded).
// ---------------------------------------------------------------------------
__global__ __launch_bounds__(256) void prepass(
    const float* __restrict__ x, const float* __restrict__ w_qkv,
    const float* __restrict__ w_out, unsigned short* __restrict__ xb,
    unsigned short* __restrict__ WqT, unsigned short* __restrict__ WoT,
    const float* __restrict__ log_scale)
{
    __shared__ float t[32][33];
    if (blockIdx.x < 4096) {
        const size_t i = ((size_t)blockIdx.x * 256 + threadIdx.x) * 8;
        const float4 a = *(const float4*)(x + i);
        const float4 b = *(const float4*)(x + i + 4);
        bf16x8 o;
        o[0] = (short)f2bf(a.x); o[1] = (short)f2bf(a.y);
        o[2] = (short)f2bf(a.z); o[3] = (short)f2bf(a.w);
        o[4] = (short)f2bf(b.x); o[5] = (short)f2bf(b.y);
        o[6] = (short)f2bf(b.z); o[7] = (short)f2bf(b.w);
        *(bf16x8*)(xb + i) = o;
    } else {
        const int bb = blockIdx.x - 4096;   // 0..1023
        const int bx = bb & 63;             // 0..63
        const int by = bb >> 6;             // 0..15
        const int tx = threadIdx.x & 31, ty = threadIdx.x >> 5;
        const int k0 = by * 32;
        const float* W; unsigned short* WT; int N, n0;
        float sc = 1.0f;
        if (bx < 48) {
            W = w_qkv; WT = WqT; N = 1536; n0 = bx * 32;
            if (n0 < 512) sc = __expf(log_scale[0]) * 1.4426950408889634f;
        } else {
            W = w_out; WT = WoT; N = 512; n0 = (bx - 48) * 32;
        }
        #pragma unroll
        for (int s = 0; s < 32; s += 8)
            t[ty + s][tx] = W[(size_t)(k0 + ty + s) * N + n0 + tx];
        __syncthreads();
        #pragma unroll
        for (int s = 0; s < 32; s += 8)
            WT[(size_t)(n0 + ty + s) * DIMK + k0 + tx] = f2bf(t[tx][ty + s] * sc);
    }
}

// ---------------------------------------------------------------------------
// MFMA GEMM 1 (R13-verified config, restored: BK=32 mainloop — R14 re-tested
// BK=64 with occupancy held constant and it still regressed ~6us; the BK
// lever is closed).  Transposed epilogues (R13-verified): Q/K [row][col]
// staging -> 16B/lane stores; V [col][row] -> V^T 16B/lane stores.  The
// coalesced Q/K writes also leave L2 in a state that speeds attn's Q-frag
// reads by ~3us (consistent across R13/R14).
// ---------------------------------------------------------------------------
__global__ __launch_bounds__(256) void gemm_qkv_mfma(
    const unsigned short* __restrict__ Xb, const unsigned short* __restrict__ WT,
    unsigned short* __restrict__ Qb, unsigned short* __restrict__ Kb,
    unsigned short* __restrict__ VTb)
{
    // pool: mainloop uses [0..8191] as As/Bs; epilogues reuse all of it
    __shared__ __align__(16) unsigned short pool[128 * 136];   // 34816 B
    unsigned short* As = pool;
    unsigned short* Bs = pool + 4096;
    const int tid = threadIdx.x, wave = tid >> 6, lane = tid & 63;
    const int l16 = lane & 15, quad = lane >> 4;
    const int m0 = blockIdx.x * 128;
    const int cb = blockIdx.y;
    const int col0 = cb * 128;
    const int wrow = wave >> 1, wcol = wave & 1;

    unsigned short* lA0 = As + (wave * 16) * 32;
    unsigned short* lA1 = As + (64 + wave * 16) * 32;
    unsigned short* lB0 = Bs + (wave * 16) * 32;
    unsigned short* lB1 = Bs + (64 + wave * 16) * 32;
    const unsigned short* gA = Xb + (size_t)(m0 + wave * 16 + (lane >> 2)) * DIMK + (lane & 3) * 8;
    const unsigned short* gB = WT + (size_t)(col0 + wave * 16 + (lane >> 2)) * DIMK + (lane & 3) * 8;

    f32x4 acc[4][4];
    #pragma unroll
    for (int i = 0; i < 4; ++i)
        #pragma unroll
        for (int j = 0; j < 4; ++j) acc[i][j] = (f32x4){0.f, 0.f, 0.f, 0.f};

    for (int k0 = 0; k0 < DIMK; k0 += 32) {
        __syncthreads();
        glds16(gA + k0, lA0);
        glds16(gA + (size_t)64 * DIMK + k0, lA1);
        glds16(gB + k0, lB0);
        glds16(gB + (size_t)64 * DIMK + k0, lB1);
        __syncthreads();
        bf16x8 af[4], bfr[4];
        #pragma unroll
        for (int i = 0; i < 4; ++i)
            af[i] = *(const bf16x8*)(As + (wrow * 64 + i * 16 + l16) * 32 + quad * 8);
        #pragma unroll
        for (int j = 0; j < 4; ++j)
            bfr[j] = *(const bf16x8*)(Bs + (wcol * 64 + j * 16 + l16) * 32 + quad * 8);
        #pragma unroll
        for (int i = 0; i < 4; ++i)
            #pragma unroll
            for (int j = 0; j < 4; ++j)
                acc[i][j] = __builtin_amdgcn_mfma_f32_16x16x32_bf16(af[i], bfr[j], acc[i][j], 0, 0, 0);
    }

    const int which = cb >> 2;   // 0=Q 1=K 2=V, uniform per block
    const int bb   = m0 >> 11;
    const int n0g  = m0 & 2047;
    const int w0   = col0 & 511;
    if (which == 2) {
        // ---- V: LDS-transposed epilogue ([col][row] staging) ----
        __syncthreads();   // everyone done with As/Bs; reuse pool
        #pragma unroll
        for (int i = 0; i < 4; ++i) {
            #pragma unroll
            for (int j = 0; j < 4; ++j) {
                const int c  = wcol * 64 + j * 16 + l16;
                const int n0 = wrow * 64 + i * 16 + quad * 4;
                uint2 w;
                w.x = (unsigned int)f2bf(acc[i][j][0]) | ((unsigned int)f2bf(acc[i][j][1]) << 16);
                w.y = (unsigned int)f2bf(acc[i][j][2]) | ((unsigned int)f2bf(acc[i][j][3]) << 16);
                *(uint2*)(&pool[c * 136 + n0]) = w;
            }
        }
        __syncthreads();
        const int cbase = tid >> 4;     // 0..15
        const int ln16  = tid & 15;
        #pragma unroll
        for (int pass = 0; pass < 8; ++pass) {
            const int cc = pass * 16 + cbase;           // 0..127
            const int w  = w0 + cc;
            const int h  = w >> 6, d = w & 63;
            const size_t bh = (size_t)(bb * HEADS + h);
            const bf16x8 val = *(const bf16x8*)(&pool[cc * 136 + ln16 * 8]);
            *(bf16x8*)(VTb + (bh * DHEAD + d) * NSEQ + n0g + ln16 * 8) = val;
        }
    } else {
        // ---- Q/K: LDS-transposed epilogue ([row][col] staging, R13) ----
        unsigned short* dstb = (which == 0) ? Qb : Kb;
        __syncthreads();   // everyone done with As/Bs; reuse pool
        #pragma unroll
        for (int i = 0; i < 4; ++i) {
            #pragma unroll
            for (int j = 0; j < 4; ++j) {
                const int c  = wcol * 64 + j * 16 + l16;
                const int r0 = wrow * 64 + i * 16 + quad * 4;
                #pragma unroll
                for (int r = 0; r < 4; ++r)
                    pool[(r0 + r) * 136 + c] = f2bf(acc[i][j][r]);
            }
        }
        __syncthreads();
        const int cbase = tid >> 4;     // 0..15 (row group)
        const int ln16  = tid & 15;     // 8-col chunk
        const int w     = w0 + ln16 * 8;
        const int h     = w >> 6, d = w & 63;
        const size_t bh = (size_t)(bb * HEADS + h);
        #pragma unroll
        for (int pass = 0; pass < 8; ++pass) {
            const int row = pass * 16 + cbase;          // 0..127
            const int n   = n0g + row;
            const bf16x8 val = *(const bf16x8*)(&pool[row * 136 + ln16 * 8]);
            *(bf16x8*)(dstb + (bh * NSEQ + n) * DHEAD + d) = val;
        }
    }
}

// ---------------------------------------------------------------------------
// MFMA GEMM 2 (R8-verified, BK=32 — 16KB LDS = 8 blocks/CU).
// out = O @ w_out + b_out (fp32 output).
// ---------------------------------------------------------------------------
__global__ __launch_bounds__(256) void gemm_out_mfma(
    const unsigned short* __restrict__ Ab, const unsigned short* __restrict__ BT,
    const float* __restrict__ bias, float* __restrict__ C)
{
    __shared__ unsigned short As[128 * 32];
    __shared__ unsigned short Bs[128 * 32];
    const int tid = threadIdx.x, wave = tid >> 6, lane = tid & 63;
    const int l16 = lane & 15, quad = lane >> 4;
    const int m0 = blockIdx.x * 128, col0 = blockIdx.y * 128;
    const int wrow = wave >> 1, wcol = wave & 1;

    unsigned short* lA0 = As + (wave * 16) * 32;
    unsigned short* lA1 = As + (64 + wave * 16) * 32;
    unsigned short* lB0 = Bs + (wave * 16) * 32;
    unsigned short* lB1 = Bs + (64 + wave * 16) * 32;
    const unsigned short* gA = Ab + (size_t)(m0 + wave * 16 + (lane >> 2)) * DIMK + (lane & 3) * 8;
    const unsigned short* gB = BT + (size_t)(col0 + wave * 16 + (lane >> 2)) * DIMK + (lane & 3) * 8;

    f32x4 acc[4][4];
    #pragma unroll
    for (int i = 0; i < 4; ++i)
        #pragma unroll
        for (int j = 0; j < 4; ++j) acc[i][j] = (f32x4){0.f, 0.f, 0.f, 0.f};

    for (int k0 = 0; k0 < DIMK; k0 += 32) {
        __syncthreads();
        glds16(gA + k0, lA0);
        glds16(gA + (size_t)64 * DIMK + k0, lA1);
        glds16(gB + k0, lB0);
        glds16(gB + (size_t)64 * DIMK + k0, lB1);
        __syncthreads();
        bf16x8 af[4], bfr[4];
        #pragma unroll
        for (int i = 0; i < 4; ++i)
            af[i] = *(const bf16x8*)(As + (wrow * 64 + i * 16 + l16) * 32 + quad * 8);
        #pragma unroll
        for (int j = 0; j < 4; ++j)
            bfr[j] = *(const bf16x8*)(Bs + (wcol * 64 + j * 16 + l16) * 32 + quad * 8);
        #pragma unroll
        for (int i = 0; i < 4; ++i)
            #pragma unroll
            for (int j = 0; j < 4; ++j)
                acc[i][j] = __builtin_amdgcn_mfma_f32_16x16x32_bf16(af[i], bfr[j], acc[i][j], 0, 0, 0);
    }

    #pragma unroll
    for (int i = 0; i < 4; ++i) {
        #pragma unroll
        for (int r = 0; r < 4; ++r) {
            const int gr = m0 + wrow * 64 + i * 16 + quad * 4 + r;
            #pragma unroll
            for (int j = 0; j < 4; ++j) {
                const int col = col0 + wcol * 64 + j * 16 + l16;
                C[(size_t)gr * 512 + col] = acc[i][j][r] + bias[col];
            }
        }
    }
}

// ---------------------------------------------------------------------------
// Flash attention v15 = v14 (R11/R13/R14-verified, 87.x us) + single-swizzle
// redist (values bit-identical; -8 DS ops per iteration on the binding DS
// pipe).  8 waves/512 threads, Q-tile 256, KVBLK=64, chunk-swizzled glds16
// staging, in-register permlane transport for P, 32KB LDS, VGPR ~60.
// Grid: linear%8 == bh%8 pins each head-batch to one XCD (K/V L2-resident).
// ---------------------------------------------------------------------------
__global__ __launch_bounds__(512) void attn_mfma(
    const unsigned short* __restrict__ Qb, const unsigned short* __restrict__ Kb,
    const unsigned short* __restrict__ VTb, unsigned short* __restrict__ O)
{
    __shared__ unsigned short Ks0[2][64 * 32];   // keys x d[0:32)   (chunk-swz)
    __shared__ unsigned short Ks1[2][64 * 32];   // keys x d[32:64)  (chunk-swz)
    __shared__ unsigned short VsA[2][64 * 32];   // d x keys[0:32)   (chunk-swz)
    __shared__ unsigned short VsB[2][64 * 32];   // d x keys[32:64)  (chunk-swz)

    const int tid  = threadIdx.x;
    const int wave = tid >> 6;                 // 0..7
    const int lane = tid & 63;
    const int l16  = lane & 15;
    const int quad = lane >> 4;
    const int bh   = blockIdx.x;               // XCD partition key
    const int q0   = blockIdx.y * 256;
    const int qwA  = q0 + wave * 16;           // group A: rows q0..q0+127
    const int qwB  = q0 + 128 + wave * 16;     // group B: rows q0+128..q0+255

    const unsigned short* Qg = Qb  + (size_t)bh * NSEQ * DHEAD;
    const unsigned short* Kg = Kb  + (size_t)bh * NSEQ * DHEAD;
    const unsigned short* Vg = VTb + (size_t)bh * DHEAD * NSEQ;

    // Q B-fragments for both groups, resident all kernel
    const bf16x8 b_qA0 = *(const bf16x8*)(Qg + (size_t)(qwA + l16) * DHEAD + quad * 8);
    const bf16x8 b_qA1 = *(const bf16x8*)(Qg + (size_t)(qwA + l16) * DHEAD + 32 + quad * 8);
    const bf16x8 b_qB0 = *(const bf16x8*)(Qg + (size_t)(qwB + l16) * DHEAD + quad * 8);
    const bf16x8 b_qB1 = *(const bf16x8*)(Qg + (size_t)(qwB + l16) * DHEAD + 32 + quad * 8);

    // constant all-ones A fragment: row-sum of P via the matrix pipe
    bf16x8 a_ones;
    #pragma unroll
    for (int i = 0; i < 8; ++i) a_ones[i] = (short)0x3F80;   // bf16 1.0

    // staging roles (wave-uniform): dest = wave>>1 (Ks0,Ks1,VsA,VsB),
    // half = wave&1 (32-row half of that dest).  2 glds16 per wave per tile.
    const int dst   = wave >> 1;
    const int halfw = wave & 1;
    const int r16 = lane >> 2;                              // 0..15 (group-local row)
    const int c8s = (((lane & 3) ^ ((lane >> 4) & 3))) * 8; // swizzled 16B chunk
    const unsigned short* gsrc;
    size_t rstep;                         // elems between 16-row groups
    size_t istep;                         // elems per 64-key iteration
    unsigned short* db[2];
    if (dst == 0) {
        gsrc = Kg + (size_t)(halfw * 32 + r16) * DHEAD + c8s;
        rstep = (size_t)16 * DHEAD;  istep = (size_t)64 * DHEAD;
        db[0] = &Ks0[0][halfw * 1024];  db[1] = &Ks0[1][halfw * 1024];
    } else if (dst == 1) {
        gsrc = Kg + (size_t)(halfw * 32 + r16) * DHEAD + 32 + c8s;
        rstep = (size_t)16 * DHEAD;  istep = (size_t)64 * DHEAD;
        db[0] = &Ks1[0][halfw * 1024];  db[1] = &Ks1[1][halfw * 1024];
    } else if (dst == 2) {
        gsrc = Vg + (size_t)(halfw * 32 + r16) * NSEQ + c8s;
        rstep = (size_t)16 * NSEQ;   istep = 64;
        db[0] = &VsA[0][halfw * 1024];  db[1] = &VsA[1][halfw * 1024];
    } else {
        gsrc = Vg + (size_t)(halfw * 32 + r16) * NSEQ + 32 + c8s;
        rstep = (size_t)16 * NSEQ;   istep = 64;
        db[0] = &VsB[0][halfw * 1024];  db[1] = &VsB[1][halfw * 1024];
    }

    // swizzled read slot (group-local row of any t-tile is l16)
    const int ksl = (quad ^ ((l16 >> 2) & 3)) * 8;

    f32x4 oA[4], oB[4], laccA, laccB;
    #pragma unroll
    for (int t = 0; t < 4; ++t) { oA[t] = (f32x4){0.f,0.f,0.f,0.f}; oB[t] = (f32x4){0.f,0.f,0.f,0.f}; }
    laccA = (f32x4){0.f,0.f,0.f,0.f};
    laccB = (f32x4){0.f,0.f,0.f,0.f};

    // prologue: stage tile 0 into buffer 0
    {
        unsigned short* d0 = db[0];
        glds16(gsrc,         d0);
        glds16(gsrc + rstep, d0 + 512);
        gsrc += istep;
    }

    #pragma unroll 2
    for (int it = 0; it < NSEQ / 64; ++it) {
        const int cur = it & 1;
        const int j0  = it * 64;
        __syncthreads();   // buffer `cur` staged; everyone done with `cur^1`

        if (it < NSEQ / 64 - 1) {   // prefetch next tile into the other buffer
            unsigned short* dn = db[cur ^ 1];
            glds16(gsrc,         dn);
            glds16(gsrc + rstep, dn + 512);
            gsrc += istep;
        }

        // ---- S^T = K Q^T (4 m-tiles of 16 keys); p = exp2(s); diag mask ----
        float pA[4][4], pB[4][4];
        #pragma unroll
        for (int t = 0; t < 4; ++t) {
            const bf16x8 a0 = *(const bf16x8*)(&Ks0[cur][(t * 16 + l16) * 32 + ksl]);
            const bf16x8 a1 = *(const bf16x8*)(&Ks1[cur][(t * 16 + l16) * 32 + ksl]);
            f32x4 sA = (f32x4){0.f,0.f,0.f,0.f}, sB = (f32x4){0.f,0.f,0.f,0.f};
            sA = __builtin_amdgcn_mfma_f32_16x16x32_bf16(a0, b_qA0, sA, 0, 0, 0);
            sA = __builtin_amdgcn_mfma_f32_16x16x32_bf16(a1, b_qA1, sA, 0, 0, 0);
            sB = __builtin_amdgcn_mfma_f32_16x16x32_bf16(a0, b_qB0, sB, 0, 0, 0);
            sB = __builtin_amdgcn_mfma_f32_16x16x32_bf16(a1, b_qB1, sB, 0, 0, 0);
            #pragma unroll
            for (int r = 0; r < 4; ++r) { pA[t][r] = fexp2(sA[r]); pB[t][r] = fexp2(sB[r]); }
            if (j0 + 16 * t == qwA) {   // wave-uniform
                #pragma unroll
                for (int r = 0; r < 4; ++r) if (l16 == quad * 4 + r) pA[t][r] = 0.f;
            }
            if (j0 + 16 * t == qwB) {
                #pragma unroll
                for (int r = 0; r < 4; ++r) if (l16 == quad * 4 + r) pB[t][r] = 0.f;
            }
        }

        // ---- pack P dwords; in-register quad redistribution ----
        unsigned wAx[4], wAy[4], wBx[4], wBy[4];
        #pragma unroll
        for (int t = 0; t < 4; ++t) {
            wAx[t] = pk_bf_trunc(pA[t][1], pA[t][0]);
            wAy[t] = pk_bf_trunc(pA[t][3], pA[t][2]);
            wBx[t] = pk_bf_trunc(pB[t][1], pB[t][0]);
            wBy[t] = pk_bf_trunc(pB[t][3], pB[t][2]);
        }
        union U8 { unsigned u[4]; bf16x8 v; } fA0, fA1, fB0, fB1;
        const bool qodd = (quad & 1) != 0;
        redist(wAx[0], wAx[1], qodd, fA0.u[0], fA0.u[2]);
        redist(wAy[0], wAy[1], qodd, fA0.u[1], fA0.u[3]);
        redist(wAx[2], wAx[3], qodd, fA1.u[0], fA1.u[2]);
        redist(wAy[2], wAy[3], qodd, fA1.u[1], fA1.u[3]);
        redist(wBx[0], wBx[1], qodd, fB0.u[0], fB0.u[2]);
        redist(wBy[0], wBy[1], qodd, fB0.u[1], fB0.u[3]);
        redist(wBx[2], wBx[3], qodd, fB1.u[0], fB1.u[2]);
        redist(wBy[2], wBy[3], qodd, fB1.u[1], fB1.u[3]);
        const bf16x8 b_pA0 = fA0.v, b_pA1 = fA1.v;
        const bf16x8 b_pB0 = fB0.v, b_pB1 = fB1.v;

        // ---- row-sums via ones-MFMA; O^T += V^T P^T (two 32-key halves) ----
        laccA = __builtin_amdgcn_mfma_f32_16x16x32_bf16(a_ones, b_pA0, laccA, 0, 0, 0);
        laccA = __builtin_amdgcn_mfma_f32_16x16x32_bf16(a_ones, b_pA1, laccA, 0, 0, 0);
        laccB = __builtin_amdgcn_mfma_f32_16x16x32_bf16(a_ones, b_pB0, laccB, 0, 0, 0);
        laccB = __builtin_amdgcn_mfma_f32_16x16x32_bf16(a_ones, b_pB1, laccB, 0, 0, 0);
        #pragma unroll
        for (int t = 0; t < 4; ++t) {
            const bf16x8 vA = *(const bf16x8*)(&VsA[cur][(t * 16 + l16) * 32 + ksl]);
            const bf16x8 vB = *(const bf16x8*)(&VsB[cur][(t * 16 + l16) * 32 + ksl]);
            oA[t] = __builtin_amdgcn_mfma_f32_16x16x32_bf16(vA, b_pA0, oA[t], 0, 0, 0);
            oA[t] = __builtin_amdgcn_mfma_f32_16x16x32_bf16(vB, b_pA1, oA[t], 0, 0, 0);
            oB[t] = __builtin_amdgcn_mfma_f32_16x16x32_bf16(vA, b_pB0, oB[t], 0, 0, 0);
            oB[t] = __builtin_amdgcn_mfma_f32_16x16x32_bf16(vB, b_pB1, oB[t], 0, 0, 0);
        }
    }

    // ---- epilogue: l is per-lane in every acc reg ----
    const float invA = 1.0f / laccA[0];
    const float invB = 1.0f / laccB[0];
    const int bb = bh >> 3, h = bh & 7;
    {
        const int n = qwA + l16;
        unsigned short* Orow = O + ((size_t)(bb * NSEQ + n)) * 512 + h * 64;
        #pragma unroll
        for (int t = 0; t < 4; ++t) {
            ushort4 o4;
            o4.x = f2bf(oA[t][0] * invA); o4.y = f2bf(oA[t][1] * invA);
            o4.z = f2bf(oA[t][2] * invA); o4.w = f2bf(oA[t][3] * invA);
            *(ushort4*)(Orow + t * 16 + quad * 4) = o4;
        }
    }
    {
        const int n = qwB + l16;
        unsigned short* Orow = O + ((size_t)(bb * NSEQ + n)) * 512 + h * 64;
        #pragma unroll
        for (int t = 0; t < 4; ++t) {
            ushort4 o4;
            o4.x = f2bf(oB[t][0] * invB); o4.y = f2bf(oB[t][1] * invB);
            o4.z = f2bf(oB[t][2] * invB); o4.w = f2bf(oB[t][3] * invB);
            *(ushort4*)(Orow + t * 16 + quad * 4) = o4;
        }
    }
}

extern "C" void kernel_launch(void* const* d_in, const int* in_sizes, int n_in,
                              void* d_out, int out_size, void* d_ws, size_t ws_size,
                              hipStream_t stream) {
    const float* x         = (const float*)d_in[0];
    const float* w_qkv     = (const float*)d_in[1];
    const float* w_out     = (const float*)d_in[2];
    const float* b_out     = (const float*)d_in[3];
    const float* log_scale = (const float*)d_in[4];
    float* out = (float*)d_out;

    char* ws = (char*)d_ws;
    const size_t NQKV = (size_t)NB * HEADS * NSEQ * DHEAD;        // 8,388,608 elems
    unsigned short* xb  = (unsigned short*)(ws);
    unsigned short* Qb  = (unsigned short*)(ws + 2 * NQKV);
    unsigned short* Kb  = (unsigned short*)(ws + 4 * NQKV);
    unsigned short* VTb = (unsigned short*)(ws + 6 * NQKV);
    unsigned short* Ofb = (unsigned short*)(ws + 8 * NQKV);
    unsigned short* WqT = (unsigned short*)(ws + 10 * NQKV);
    unsigned short* WoT = (unsigned short*)(ws + 10 * NQKV + 4 * 1024 * 1024);

    prepass<<<4096 + 1024, 256, 0, stream>>>(x, w_qkv, w_out, xb, WqT, WoT, log_scale);

    gemm_qkv_mfma<<<dim3(M_TOT / 128, 1536 / 128), 256, 0, stream>>>(xb, WqT, Qb, Kb, VTb);

    attn_mfma<<<dim3(NB * HEADS, NSEQ / 256), 512, 0, stream>>>(Qb, Kb, VTb, Ofb);

    gemm_out_mfma<<<dim3(M_TOT / 128, 512 / 128), 256, 0, stream>>>(Ofb, WoT, b_out, out);
}